// Round 8
// baseline (335.792 us; speedup 1.0000x reference)
//
#include <hip/hip_runtime.h>

#define EPSV 1e-5f

typedef __bf16 bf16x8 __attribute__((ext_vector_type(8)));
typedef float f32x4 __attribute__((ext_vector_type(4)));
typedef float f32x2 __attribute__((ext_vector_type(2)));
typedef unsigned short ushort8 __attribute__((ext_vector_type(8)));

// ---------------- K0: weight fragments + folded biases + BN1 coeffs ----------------
// B-fragment layout for mfma_f32_16x16x32_bf16:
//   element (tap, half, lane, j) = w'[co = half*16 + (lane&15)][ci = (lane>>4)*8 + j][tap]
__global__ __launch_bounds__(256) void prep_weights(
    const float* __restrict__ w1, const float* __restrict__ b1,
    const float* __restrict__ g2, const float* __restrict__ be2,
    const float* __restrict__ m2, const float* __restrict__ v2,
    const float* __restrict__ w2,
    const float* __restrict__ g1, const float* __restrict__ be1,
    const float* __restrict__ m1, const float* __restrict__ v1,
    __bf16* __restrict__ wf1, __bf16* __restrict__ wf2,
    float* __restrict__ bias1p, float* __restrict__ sc1, float* __restrict__ sf1) {
  int i = blockIdx.x * 256 + threadIdx.x;   // 0..18431
  int conv = i / 9216;
  int rem  = i % 9216;
  int tap  = rem >> 10;          // 0..8
  int r2   = rem & 1023;
  int half = r2 >> 9;
  int lane = (r2 >> 3) & 63;
  int j    = r2 & 7;
  int ci = ((lane >> 4) << 3) + j;
  int co = half * 16 + (lane & 15);
  float val = (conv ? w2 : w1)[(co * 32 + ci) * 9 + tap];
  if (!conv) val *= g2[co] * rsqrtf(v2[co] + EPSV);   // fold BN2 scale into w1
  (conv ? wf2 : wf1)[rem] = (__bf16)val;
  if (blockIdx.x == 0 && threadIdx.x < 32) {
    int c = threadIdx.x;
    float s2 = g2[c] * rsqrtf(v2[c] + EPSV);
    bias1p[c] = s2 * b1[c] + (be2[c] - m2[c] * s2);   // scale2*b1 + shift2
  }
  if (blockIdx.x == 0 && threadIdx.x >= 64 && threadIdx.x < 96) {
    int c = threadIdx.x - 64;
    float s = g1[c] * rsqrtf(v1[c] + EPSV);
    sc1[c] = s;
    sf1[c] = be1[c] - m1[c] * s;
  }
}

// ---------------- K1: fully fused, 512 thr / 8 waves, 6-row x 64-px-half strips ----
// LDS: 10 slots x [80 px][32 ch] bf16 (5120 B/slot, 50 KiB). px window = [P0-8, P0+71].
// chunk swizzle: 8-ch chunk c>>3 of pixel lp stored at 16B slot s = (c>>3) ^ ((lp>>1)&3).
// Phases: stage 10 BN1+ReLU'd x rows -> BAR -> wave w computes h row (w-1) in regs
// (90 MFMA) -> BAR -> h row w-1 overwrites slot w (x slots retired); h zeroed outside
// image px (conv2 padding semantics) -> BAR -> conv2: 24 tasks (6 rows x 4 px-groups)
// = 3/wave, direct D-fragment store + residual.
__global__ __launch_bounds__(512, 4) void fused6(
    const float* __restrict__ x,
    const float* __restrict__ sc1v, const float* __restrict__ sf1v,
    const __bf16* __restrict__ wf1, const __bf16* __restrict__ wf2,
    const float* __restrict__ bias1p, const float* __restrict__ b2,
    float* __restrict__ outf) {
  __shared__ __align__(16) unsigned short tile[10 * 2560];   // 51200 B
  char* tb = reinterpret_cast<char*>(tile);
  int t = threadIdx.x, lane = t & 63, wv = t >> 6;
  int logical = ((blockIdx.x & 7) * 352) + (blockIdx.x >> 3);  // XCD-bijective (2816=8*352)
  int half = logical & 1;
  int sb = logical >> 1;          // 0..1407
  int strip = sb % 22;
  int b = sb / 22;
  int h0 = strip * 6;             // strip 21: rows 126..131, tail masked
  int P0 = half << 6;

  // ---- stage: 1600 tasks = 10 slots x 4 chunks x 40 px-pairs ----
  #pragma unroll
  for (int i = 0; i < 4; i++) {
    int task = t + 512 * i;
    if (task < 1600) {
      int slot = task / 160;
      int rm = task - slot * 160;
      int chunk = rm / 40;
      int pair = rm - chunk * 40;
      int hr = h0 - 2 + slot;
      int gpx = P0 - 8 + 2 * pair;
      char* dst = tb + slot * 5120 + pair * 128 + ((chunk ^ (pair & 3)) << 4);
      if (hr >= 0 && hr < 128 && gpx >= 0 && gpx <= 126) {
        const float* src = x + ((long)(b * 32 + chunk * 8) * 128 + hr) * 128 + gpx;
        f32x4 s0 = *reinterpret_cast<const f32x4*>(sc1v + chunk * 8);
        f32x4 s1 = *reinterpret_cast<const f32x4*>(sc1v + chunk * 8 + 4);
        f32x4 f0 = *reinterpret_cast<const f32x4*>(sf1v + chunk * 8);
        f32x4 f1 = *reinterpret_cast<const f32x4*>(sf1v + chunk * 8 + 4);
        bf16x8 a0, a1;
        #pragma unroll
        for (int cc = 0; cc < 8; cc++) {
          f32x2 v = *reinterpret_cast<const f32x2*>(src + cc * 16384);
          float s = cc < 4 ? s0[cc & 3] : s1[cc & 3];
          float f = cc < 4 ? f0[cc & 3] : f1[cc & 3];
          a0[cc] = (__bf16)fmaxf(fmaf(v[0], s, f), 0.0f);
          a1[cc] = (__bf16)fmaxf(fmaf(v[1], s, f), 0.0f);
        }
        *reinterpret_cast<bf16x8*>(dst) = a0;
        *reinterpret_cast<bf16x8*>(dst + 64) = a1;
      } else {
        *reinterpret_cast<bf16x8*>(dst) = bf16x8{};
        *reinterpret_cast<bf16x8*>(dst + 64) = bf16x8{};
      }
    }
  }

  // conv1 weights -> 72 VGPRs (loaded after staging issues; dead before conv2)
  bf16x8 Bf1[9][2];
  #pragma unroll
  for (int tap = 0; tap < 9; tap++)
    #pragma unroll
    for (int hf = 0; hf < 2; hf++)
      Bf1[tap][hf] = reinterpret_cast<const bf16x8*>(wf1)[(tap * 2 + hf) * 64 + lane];
  float bco1[2] = { bias1p[lane & 15], bias1p[16 + (lane & 15)] };
  float bco2[2] = { b2[lane & 15], b2[16 + (lane & 15)] };

  int cb = lane >> 4;
  int l15 = lane & 15;

  __syncthreads();

  // ---- conv1: wave wv -> h row m = wv-1, from x slots wv..wv+2, into regs ----
  // Per-(g,dx) pixel lp = g*16 + l15 + dx - 1, computed exactly (clamp+mask only
  // for true OOB lp=-1 / lp=80). dy-invariant offsets hoisted by the compiler.
  int hrow = h0 + wv - 1;
  bool hvalid = (hrow >= 0) && (hrow < 128);
  f32x4 hacc[5][2] = {};
  if (hvalid) {
    #pragma unroll
    for (int dy = 0; dy < 3; dy++) {
      const char* rb = tb + (wv + dy) * 5120;
      #pragma unroll
      for (int dx = 0; dx < 3; dx++) {
        #pragma unroll
        for (int g = 0; g < 5; g++) {
          int lp = g * 16 + l15 + dx - 1;         // -1..80
          bool bad = (unsigned)lp > 79u;          // lp==-1 or lp==80
          int lpc = bad ? (lp < 0 ? 0 : 79) : lp;
          int off = lpc * 64 + ((cb ^ ((lpc >> 1) & 3)) << 4);
          bf16x8 a = *reinterpret_cast<const bf16x8*>(rb + off);
          if (bad) a = bf16x8{};
          hacc[g][0] = __builtin_amdgcn_mfma_f32_16x16x32_bf16(a, Bf1[dy * 3 + dx][0], hacc[g][0], 0, 0, 0);
          hacc[g][1] = __builtin_amdgcn_mfma_f32_16x16x32_bf16(a, Bf1[dy * 3 + dx][1], hacc[g][1], 0, 0, 0);
        }
      }
    }
  }
  __syncthreads();

  // ---- write h row m (ReLU + bias, bf16) into slot wv; OOB rows -> zeros ----
  // h zeroed where global px outside [0,127]: conv2 must see zero-padding there.
  {
    char* hslot = tb + wv * 5120;
    if (hvalid) {
      #pragma unroll
      for (int g = 0; g < 5; g++)
        #pragma unroll
        for (int hf = 0; hf < 2; hf++) {
          int co = hf * 16 + l15;
          #pragma unroll
          for (int j = 0; j < 4; j++) {
            int lp = g * 16 + ((lane >> 4) << 2) + j;
            float val = fmaxf(hacc[g][hf][j] + bco1[hf], 0.0f);
            if ((unsigned)(P0 - 8 + lp) >= 128u) val = 0.0f;   // image W-edge padding
            int byte = lp * 64 + (((co >> 3) ^ ((lp >> 1) & 3)) << 4) + (co & 7) * 2;
            *reinterpret_cast<unsigned short*>(hslot + byte) =
                __builtin_bit_cast(unsigned short, (__bf16)val);
          }
        }
    } else {
      #pragma unroll
      for (int q = 0; q < 5; q++)
        *reinterpret_cast<ushort8*>(hslot + lane * 16 + q * 1024) = ushort8{};
    }
  }
  __syncthreads();

  // ---- conv2: tasks (row r, px-group g2), 3 per wave; h slots r..r+2 ----
  #pragma unroll
  for (int i = 0; i < 3; i++) {
    int task = wv * 3 + i;         // 0..23
    int r = task >> 2, g2 = task & 3;
    int hr = h0 + r;
    int o2[3];
    #pragma unroll
    for (int dx = 0; dx < 3; dx++) {
      int lp = 8 + g2 * 16 + l15 + dx - 1;   // 7..72, always in-slot
      o2[dx] = lp * 64 + ((cb ^ ((lp >> 1) & 3)) << 4);
    }
    f32x4 c2[2] = {};
    #pragma unroll
    for (int dy = 0; dy < 3; dy++) {
      const char* rb = tb + (r + dy) * 5120;
      #pragma unroll
      for (int dx = 0; dx < 3; dx++) {
        int tap = dy * 3 + dx;
        bf16x8 a = *reinterpret_cast<const bf16x8*>(rb + o2[dx]);
        bf16x8 B0 = reinterpret_cast<const bf16x8*>(wf2)[(tap * 2 + 0) * 64 + lane];
        bf16x8 B1 = reinterpret_cast<const bf16x8*>(wf2)[(tap * 2 + 1) * 64 + lane];
        c2[0] = __builtin_amdgcn_mfma_f32_16x16x32_bf16(a, B0, c2[0], 0, 0, 0);
        c2[1] = __builtin_amdgcn_mfma_f32_16x16x32_bf16(a, B1, c2[1], 0, 0, 0);
      }
    }
    if (hr < 128) {
      #pragma unroll
      for (int hf = 0; hf < 2; hf++) {
        int co = hf * 16 + l15;
        int gpx0 = P0 + g2 * 16 + ((lane >> 4) << 2);
        long idx = ((long)(b * 32 + co) * 128 + hr) * 128 + gpx0;
        f32x4 xr = *reinterpret_cast<const f32x4*>(x + idx);
        f32x4 o;
        #pragma unroll
        for (int j = 0; j < 4; j++) o[j] = c2[hf][j] + bco2[hf] + xr[j];
        *reinterpret_cast<f32x4*>(outf + idx) = o;
      }
    }
  }
}

extern "C" void kernel_launch(void* const* d_in, const int* in_sizes, int n_in,
                              void* d_out, int out_size, void* d_ws, size_t ws_size,
                              hipStream_t stream) {
  const float* x   = (const float*)d_in[0];
  const float* g1  = (const float*)d_in[1];
  const float* be1 = (const float*)d_in[2];
  const float* m1  = (const float*)d_in[3];
  const float* v1  = (const float*)d_in[4];
  const float* w1  = (const float*)d_in[5];
  const float* b1  = (const float*)d_in[6];
  const float* g2  = (const float*)d_in[7];
  const float* be2 = (const float*)d_in[8];
  const float* m2  = (const float*)d_in[9];
  const float* v2  = (const float*)d_in[10];
  const float* w2  = (const float*)d_in[11];
  const float* b2  = (const float*)d_in[12];

  char* ws = (char*)d_ws;
  __bf16* wf1    = (__bf16*)ws;                  // 18432 B
  __bf16* wf2    = (__bf16*)(ws + 18432);        // 18432 B
  float*  bias1p = (float*)(ws + 36864);         // 128 B
  float*  sc1    = (float*)(ws + 36992);         // 128 B
  float*  sf1    = (float*)(ws + 37120);         // 128 B

  prep_weights<<<dim3(72), dim3(256), 0, stream>>>(
      w1, b1, g2, be2, m2, v2, w2, g1, be1, m1, v1, wf1, wf2, bias1p, sc1, sf1);
  fused6<<<dim3(2816), dim3(512), 0, stream>>>(
      x, sc1, sf1, wf1, wf2, bias1p, b2, (float*)d_out);
}